// Round 12
// baseline (2618.002 us; speedup 1.0000x reference)
//
#include <hip/hip_runtime.h>
#include <math.h>

// B = T = 1000, N = 128, D = 64. Replicated sim (r11 win): 250 independent
// blocks each recompute the identical f64 trajectory and write 4 batch rows.
// Round 12: attack the ~2760 cy/step serial scan (VALU-issue + LDS-latency):
//   - wrec staged as f64 in LDS (129 rows x 128 x 8B = 129KB, 1 block/CU):
//     consume = bare v_add_f64 (deletes cvt+cndmask per element)
//   - zero-row padding (row 128 = 0.0): pad slots add exact +0.0, no selects
//   - branchless 2-batch pipeline: counted uniform pair loop, fixed A/B reg
//     roles; batch k+1's 8 ds_read_b128 in flight under batch k's adds
//   - adjacent-neuron layout (lane owns 2l,2l+1): b128 gather reads, vf2
//     stores (8/step), vd2 x-loads; evens-then-odds order + syn*0.1
//     (both r10-validated: identical absmax 0.0625)
// Dispatch-sum accounting (r11): harness floor ~780us is constant; metric is
// the kernel sum. inpcur/fixup unchanged.

#define XCHUNK 8   // input-current register prefetch depth (steps)
#define NBLK   250 // sim replicas; each owns rows j + k*NBLK, k=0..3

typedef float  vf4 __attribute__((ext_vector_type(4)));
typedef float  vf2 __attribute__((ext_vector_type(2)));
typedef double vd2 __attribute__((ext_vector_type(2)));

// ---------------------------------------------------------------------------
// Kernel 1: inp_cur[t][n] = sum_d sig[t][d] * win[d][n]  (float64 accumulate)
// UNCHANGED numerics (bit-exact reproducibility).
// ---------------------------------------------------------------------------
__global__ void inpcur_kernel(const float* __restrict__ sig,
                              const float* __restrict__ win,
                              double* __restrict__ inp_cur,
                              int D, int N) {
    const int t = blockIdx.x;
    const int n = threadIdx.x;
    const float* srow = sig + (size_t)t * D;
    double acc = 0.0;
    for (int d = 0; d < D; ++d)
        acc += (double)srow[d] * (double)win[(size_t)d * N + n];
    inp_cur[(size_t)t * N + n] = acc;
}

// ---------------------------------------------------------------------------
// Kernel 2: replicated 1000-step LIF scan. ONE wave per block; lane l owns
// neurons 2l and 2l+1. Sparse recurrent gather: evens ascending then odds
// ascending, batches of 8 ds_read_b128 from f64 LDS, two-batch pipelined.
// Membrane rows B-3 and B-2 are skipped (they hold the inp_cur scratch).
// ---------------------------------------------------------------------------
__global__ __launch_bounds__(64, 1) void simrep_kernel(
    const double* __restrict__ inp_cur,
    const float* __restrict__ wrec,
    float* __restrict__ out,      // full output base
    long long TN, long long B_TN, int B, int nt) {
    __shared__ double lds_w64[129 * 128];  // 129 KiB: wrec as f64 + zero row

    const int l = threadIdx.x;  // lane 0..63
    const int j = blockIdx.x;   // replica id 0..NBLK-1

    __builtin_amdgcn_s_setprio(3);

    // Per-block output row bases (wave-uniform -> SGPRs).
    float* spk[4];
    float* mem[4];
    bool   wmem[4];
    int    rows[4];
    #pragma unroll
    for (int k = 0; k < 4; ++k) {
        rows[k] = j + k * NBLK;                    // covers 0..999 bijectively
        spk[k]  = out + (long long)rows[k] * TN;
        mem[k]  = out + B_TN + (long long)rows[k] * TN;
        wmem[k] = (rows[k] != B - 3) && (rows[k] != B - 2);  // scratch rows
    }
    float* trace = out + 2 * B_TN;

    // Stage wrec (f32 global, coalesced vf4) -> f64 LDS; zero row 128.
    {
        const vf4* src = (const vf4*)wrec;       // 4096 vf4
        vd2* dst = (vd2*)lds_w64;
        for (int i = 0; i < 64; ++i) {
            const vf4 v = src[i * 64 + l];
            const int e = (i * 64 + l) * 2;      // vd2 index
            vd2 a; a.x = (double)v.x; a.y = (double)v.y;
            vd2 b; b.x = (double)v.z; b.y = (double)v.w;
            dst[e]     = a;
            dst[e + 1] = b;
        }
        vd2 z; z.x = 0.0; z.y = 0.0;
        dst[128 * 64 + l] = z;                   // zero row (row index 128)
        // Same-wave LDS RAW handled by compiler waitcnt; no barrier needed.
    }
    const vd2* w64v = (const vd2*)lds_w64;       // w64v[k*64 + l] = row k, pair l

    double mem0 = 0.0, syn0 = 0.0, trc0 = 0.0, refr0 = 0.0, rec0 = 0.0;
    double mem1 = 0.0, syn1 = 0.0, trc1 = 0.0, refr1 = 0.0, rec1 = 0.0;

    vd2 xa[XCHUNK];

// Branchless uniform slot extraction: evens (mA, row 2l) ascending, then
// odds (mB, row 2l+1) ascending; exhausted -> zero row 128 (adds exact +0.0).
#define EXTRACT8(kk)                                                     \
    do {                                                                 \
        _Pragma("unroll") for (int jj = 0; jj < 8; ++jj) {               \
            const bool useA = (mA != 0ull);                              \
            const bool any  = ((mA | mB) != 0ull);                       \
            const unsigned long long msel = useA ? mA : mB;              \
            const int tz = (int)__builtin_ctzll(msel ? msel : 1ull);     \
            kk[jj] = any ? (useA ? 2 * tz : 2 * tz + 1) : 128;           \
            mA = useA ? (mA & (mA - 1ull)) : mA;                         \
            mB = (useA || !any) ? mB : (mB & (mB - 1ull));               \
        }                                                                \
    } while (0)

#define ISSUE8(kk, W)                                                    \
    do {                                                                 \
        _Pragma("unroll") for (int jj = 0; jj < 8; ++jj)                 \
            W[jj] = w64v[kk[jj] * 64 + l];                               \
    } while (0)

#define CONSUME8(W)                                                      \
    do {                                                                 \
        _Pragma("unroll") for (int jj = 0; jj < 8; ++jj) {               \
            add0 += W[jj].x;                                             \
            add1 += W[jj].y;                                             \
        }                                                                \
    } while (0)

    for (int t0 = 0; t0 < nt; t0 += XCHUNK) {
        const int cs = (nt - t0 < XCHUNK) ? (nt - t0) : XCHUNK;
        // Prefetch cs steps of input current (vd2 = 16B/lane, coalesced).
        #pragma unroll
        for (int s = 0; s < XCHUNK; ++s)
            if (s < cs)
                xa[s] = ((const vd2*)(inp_cur + (size_t)(t0 + s) * 128))[l];

        #pragma unroll
        for (int s = 0; s < XCHUNK; ++s) {
            if (s >= cs) break;
            const int t = t0 + s;

            syn0 = syn0 * (1.0 - 1.0 / 5.0) + xa[s].x + rec0;
            mem0 = mem0 * (1.0 - 1.0 / 10.0) + syn0 * 0.1;
            if (refr0 > 0.0) mem0 = 0.0;
            refr0 = refr0 - 1.0;
            if (refr0 < 0.0) refr0 = 0.0;
            const bool sp0 = mem0 > 1.0;

            syn1 = syn1 * (1.0 - 1.0 / 5.0) + xa[s].y + rec1;
            mem1 = mem1 * (1.0 - 1.0 / 10.0) + syn1 * 0.1;
            if (refr1 > 0.0) mem1 = 0.0;
            refr1 = refr1 - 1.0;
            if (refr1 < 0.0) refr1 = 0.0;
            const bool sp1 = mem1 > 1.0;

            // Wave-uniform spike masks in SGPRs: bit l of mA -> row 2l,
            // bit l of mB -> row 2l+1.
            unsigned long long mA = __ballot(sp0);
            unsigned long long mB = __ballot(sp1);
            const int nb =
                (int)((__popcll(mA) + __popcll(mB) + 7) >> 3);  // batches

            if (sp0) { mem0 = 0.0; refr0 += 2.0; }
            trc0 = trc0 * 0.95 + (sp0 ? 1.0 : 0.0);
            if (sp1) { mem1 = 0.0; refr1 += 2.0; }
            trc1 = trc1 * 0.95 + (sp1 ? 1.0 : 0.0);

            double add0 = 0.0, add1 = 0.0;
            int kA[8], kB[8];
            vd2 WA[8], WB[8];

            // Issue batch 0 first, then overlap its LDS latency with the
            // output stores (vf2 NT, 8B/lane each, 4 owned rows).
            if (nb) { EXTRACT8(kA); ISSUE8(kA, WA); }

            {
                vf2 sv; sv.x = sp0 ? 1.0f : 0.0f; sv.y = sp1 ? 1.0f : 0.0f;
                vf2 mv; mv.x = (float)mem0; mv.y = (float)mem1;
                #pragma unroll
                for (int k = 0; k < 4; ++k) {
                    __builtin_nontemporal_store(
                        sv, (vf2*)(spk[k] + (size_t)t * 128) + l);
                    if (wmem[k])
                        __builtin_nontemporal_store(
                            mv, (vf2*)(mem[k] + (size_t)t * 128) + l);
                }
            }

            if (nb) {
                // Two-batch pipeline, fixed A/B roles, counted uniform loop:
                // I0 | {I(B) C(A) I(A) C(B)} x npair | C(A).
                // Over-issued/consumed tail batches hit the zero row (+0.0).
                const int npair = nb >> 1;
                #pragma unroll 1
                for (int p = 0; p < npair; ++p) {
                    EXTRACT8(kB); ISSUE8(kB, WB);
                    CONSUME8(WA);                 // waits A only; B in flight
                    EXTRACT8(kA); ISSUE8(kA, WA);
                    CONSUME8(WB);                 // waits B only; A in flight
                }
                CONSUME8(WA);
            }
            rec0 = rec0 * 0.95 + add0;
            rec1 = rec1 * 0.95 + add1;
        }
    }

    // Final trace for all owned rows (trace region does not overlap scratch).
    {
        vf2 tv; tv.x = (float)trc0; tv.y = (float)trc1;
        #pragma unroll
        for (int k = 0; k < 4; ++k)
            ((vf2*)(trace + (size_t)rows[k] * 128))[l] = tv;
    }

#undef EXTRACT8
#undef ISSUE8
#undef CONSUME8
}

// ---------------------------------------------------------------------------
// Kernel 3: fixup — copy membrane row 0 over the scratch rows B-3, B-2
// (runs after simrep in stream order; scratch fully consumed by then).
// ---------------------------------------------------------------------------
__global__ void fixup_kernel(float* __restrict__ mem_base, long long TN,
                             int rowA, int rowB) {
    const long long tn4 = TN / 4;
    const long long idx = (long long)blockIdx.x * blockDim.x + threadIdx.x;
    if (idx >= 2 * tn4) return;
    const int r = (idx < tn4) ? rowA : rowB;
    const long long i = (idx < tn4) ? idx : idx - tn4;
    const vf4 v = ((const vf4*)mem_base)[i];
    __builtin_nontemporal_store(v, (vf4*)mem_base + (long long)r * tn4 + i);
}

// ---------------------------------------------------------------------------
extern "C" void kernel_launch(void* const* d_in, const int* in_sizes, int n_in,
                              void* d_out, int out_size, void* d_ws, size_t ws_size,
                              hipStream_t stream) {
    const float* sig  = (const float*)d_in[0];  // (T, D)
    const float* win  = (const float*)d_in[1];  // (D, N)
    const float* wrec = (const float*)d_in[2];  // (N, N)

    int N = 1;
    while ((long long)N * N < (long long)in_sizes[2]) ++N;   // N = 128
    const int D = in_sizes[1] / N;                            // 64
    const int B = in_sizes[0] / D;                            // 1000 (= T)
    const int nt = (int)((((long long)out_size / B) - N) / (2 * N));  // 1000

    const long long TN   = (long long)nt * N;   // 128,000
    const long long B_TN = (long long)B * TN;   // 128,000,000

    float* out = (float*)d_out;
    // f64 inp_cur scratch = membrane rows B-3, B-2 (exactly nt*N doubles).
    // simrep never writes those rows; fixup restores them afterward.
    double* inp_cur = (double*)(out + B_TN + (long long)(B - 3) * TN);

    inpcur_kernel<<<nt, N, 0, stream>>>(sig, win, inp_cur, D, N);

    simrep_kernel<<<NBLK, 64, 0, stream>>>(inp_cur, wrec, out,
                                           TN, B_TN, B, nt);

    const long long tn4 = TN / 4;
    fixup_kernel<<<(unsigned)((2 * tn4 + 255) / 256), 256, 0, stream>>>(
        out + B_TN, TN, B - 3, B - 2);
}